// Round 7
// baseline (333.322 us; speedup 1.0000x reference)
//
#include <hip/hip_runtime.h>
#include <stdint.h>

typedef unsigned long long u64;
typedef unsigned int u32;
typedef unsigned short u16;

#define N_BOXES 50000
#define N_CLS 80
#define N_IMG 8
#define KCAND 500
#define MAX_DET 300
#define CAP 1024          // per-class candidates above 0.8: mean 692, sigma 26 -> +12.7 sigma
#define PRE_THR 0.8f

#define P_BOXES 512
#define NGRP ((N_BOXES + P_BOXES - 1) / P_BOXES)  // 98
#define BUFCAP 1024       // per-block passers: mean 567, sigma 24 -> +19 sigma

// workspace layout (bytes)
#define OFF_CANDCNT 0                      // 640*4 -> 2560
#define OFF_KEPTCNT 2560                   // 640*4 -> 5120
#define OFF_IMGHIST 8192                   // 8*2048*4 = 65536 -> 73728
#define OFF_KEPTKEYS 73728                 // 640*512*8 = 2621440 -> 2695168
#define OFF_CAND 2695168                   // 640*1024*8 = 5242880 -> 7938048

__device__ __forceinline__ int bin_of(u32 sb) {
  int d = (int)(sb - 0x3F000000u);
  int bin = d < 0 ? 0 : (d >> 12);
  return bin > 2047 ? 2047 : bin;
}

__device__ __forceinline__ u64 shflx64(u64 v, int m) {
  int lo = __shfl_xor((int)(u32)v, m, 64);
  int hi = __shfl_xor((int)(v >> 32), m, 64);
  return ((u64)(u32)hi << 32) | (u32)lo;
}

__device__ __forceinline__ u64 wave_or64(u64 v) {
  for (int m = 1; m < 64; m <<= 1) v |= shflx64(v, m);
  return v;
}

// Hybrid bitonic sort, descending, S elements over S threads, 1 elt/thread.
// j<64 via cross-lane shuffle (no barrier); j>=64 via LDS exchange.
template <int S>
__device__ __forceinline__ void hybrid_sort(u64& v, u64* sbuf, int tid) {
  for (int k = 2; k <= S; k <<= 1)
    for (int j = k >> 1; j > 0; j >>= 1) {
      u64 o;
      if (j >= 64) {
        __syncthreads();
        sbuf[tid] = v;
        __syncthreads();
        o = sbuf[tid ^ j];
      } else {
        o = shflx64(v, j);
      }
      bool takeMax = (((tid & k) == 0) == ((tid & j) == 0));
      if (takeMax ? (o > v) : (o < v)) v = o;
    }
}

template <int T>
__device__ __forceinline__ void pick_threshold(u32* hist, int* partial, int* s_t, int K, int tid) {
  constexpr int G = 2048 / T;
  int ps = 0;
#pragma unroll
  for (int q = 0; q < G; ++q) ps += (int)hist[tid * G + q];
  partial[tid] = ps;
  for (int off = 1; off < T; off <<= 1) {
    __syncthreads();
    int v = partial[tid];
    if (tid + off < T) v += partial[tid + off];
    __syncthreads();
    partial[tid] = v;
  }
  if (tid == 0) *s_t = 0;
  __syncthreads();
  int sfx = partial[tid];
  int nxt = (tid == T - 1) ? 0 : partial[tid + 1];
  if (sfx >= K && nxt < K) {
    int acc = nxt;
    int bin;
    for (bin = tid * G + G - 1; bin > tid * G; --bin) {
      if (acc + (int)hist[bin] >= K) break;
      acc += (int)hist[bin];
    }
    *s_t = bin;
  }
  __syncthreads();
}

// ---------------- kernel 1: candidate compaction ----------------
__global__ __launch_bounds__(512) void k1_compact(const float* __restrict__ cls,
                                                  int* __restrict__ candCnt,
                                                  u64* __restrict__ cand) {
  __shared__ u64 bkey[BUFCAP];
  __shared__ u16 bcls[BUFCAP];
  __shared__ int cnt[N_CLS];
  __shared__ int cbase[N_CLS];
  __shared__ int cur[N_CLS];
  __shared__ int s_n;

  int tid = threadIdx.x;
  int lane = tid & 63;
  int b = blockIdx.x / NGRP, g = blockIdx.x % NGRP;
  int n0 = g * P_BOXES;
  int nb = N_BOXES - n0;
  if (nb > P_BOXES) nb = P_BOXES;
  int nf4 = nb * (N_CLS / 4);
  const float4* src = (const float4*)(cls + ((size_t)b * N_BOXES + n0) * N_CLS);

  for (int i = tid; i < N_CLS; i += 512) { cnt[i] = 0; cur[i] = 0; }
  if (tid == 0) s_n = 0;
  __syncthreads();

  for (int base = tid * 4; base < nf4; base += 2048) {
    float4 f[4];
#pragma unroll
    for (int u = 0; u < 4; ++u)
      f[u] = (base + u < nf4) ? src[base + u] : make_float4(0.f, 0.f, 0.f, 0.f);
#pragma unroll
    for (int u = 0; u < 4; ++u) {
      float ss[4] = {f[u].x, f[u].y, f[u].z, f[u].w};
      int e = (base + u) * 4;
      int nl = e / N_CLS;
      int cb = e - nl * N_CLS;
      u32 inv_n = ~(u32)(n0 + nl);
#pragma unroll
      for (int q = 0; q < 4; ++q) {
        bool pred = ss[q] > PRE_THR;
        u64 mask = __ballot(pred);
        if (mask) {
          int leader = __builtin_ctzll(mask);
          int wcnt = __builtin_popcountll(mask);
          int basep = 0;
          if (lane == leader) basep = atomicAdd(&s_n, wcnt);
          basep = __shfl(basep, leader);
          if (pred) {
            int p = basep + __builtin_popcountll(mask & ((1ull << lane) - 1ull));
            if (p < BUFCAP) {
              int c = cb + q;
              bkey[p] = ((u64)__float_as_uint(ss[q]) << 32) | (u64)inv_n;
              bcls[p] = (u16)c;
              atomicAdd(&cnt[c], 1);
            }
          }
        }
      }
    }
  }
  __syncthreads();
  int total = s_n < BUFCAP ? s_n : BUFCAP;
  if (tid < N_CLS) {
    int n = cnt[tid];
    cbase[tid] = n ? atomicAdd(&candCnt[b * N_CLS + tid], n) : 0;
  }
  __syncthreads();
  for (int i = tid; i < total; i += 512) {
    u64 key = bkey[i];
    int c = (int)bcls[i];
    int w = atomicAdd(&cur[c], 1);
    int pos = cbase[c] + w;
    if (pos < CAP) cand[(size_t)(b * N_CLS + c) * CAP + pos] = key;
  }
}

// tile order: (jb, w), w <= jb, ordered by jb then w (36 tiles)
__device__ const unsigned char TILE_JB[36] = {0, 1,1, 2,2,2, 3,3,3,3, 4,4,4,4,4,
                                              5,5,5,5,5,5, 6,6,6,6,6,6,6, 7,7,7,7,7,7,7,7};
__device__ const unsigned char TILE_W[36]  = {0, 0,1, 0,1,2, 0,1,2,3, 0,1,2,3,4,
                                              0,1,2,3,4,5, 0,1,2,3,4,5,6, 0,1,2,3,4,5,6,7};

// 64x64 suppression tile: cols[w*512 + j] bit il = (i = w*64+il < j) && IoU(i,j) > 0.5
template <bool DIAG>
__device__ __forceinline__ void mask_tile(const float4* bx, const float* areas, u64* cols,
                                          int jb, int w, int lane, int V) {
  int j = jb * 64 + lane;
  u64 sup = 0;
  if (j < V) {
    float4 bj = bx[j];
    float aj = areas[j];
    const float4* bp = bx + w * 64;
    const float* ap = areas + w * 64;
    u64 needs = 0;
#pragma unroll 16
    for (int il = 0; il < 64; ++il) {
      float4 bi = bp[il];           // immediate-offset ds_read_b128, broadcast
      float ai = ap[il];
      float yy1 = fmaxf(bi.x, bj.x);
      float xx1 = fmaxf(bi.y, bj.y);
      float yy2 = fminf(bi.z, bj.z);
      float xx2 = fminf(bi.w, bj.w);
      float ih = fmaxf(__fsub_rn(yy2, yy1), 0.0f);
      float iw = fmaxf(__fsub_rn(xx2, xx1), 0.0f);
      float inter = __fmul_rn(ih, iw);
      float denom = __fadd_rn(__fsub_rn(__fadd_rn(ai, aj), inter), 1e-9f);
      float diff = __fsub_rn(__fmul_rn(inter, 2.0f), denom);
      bool fast = diff > 0.0f;
      bool nd = fabsf(diff) <= __fmul_rn(denom, 1e-6f);
      if (DIAG) { bool lt = il < lane; fast = fast && lt; nd = nd && lt; }
      sup |= fast ? (1ull << il) : 0ull;
      needs |= nd ? (1ull << il) : 0ull;
    }
    if (needs) {  // rare: exact rounded-division decision near the boundary
      u64 nm = needs;
      while (nm) {
        int il = __builtin_ctzll(nm);
        nm &= nm - 1;
        float4 bi = bp[il];
        float ai = ap[il];
        float ih = fmaxf(__fsub_rn(fminf(bi.z, bj.z), fmaxf(bi.x, bj.x)), 0.0f);
        float iw = fmaxf(__fsub_rn(fminf(bi.w, bj.w), fmaxf(bi.y, bj.y)), 0.0f);
        float inter = __fmul_rn(ih, iw);
        float denom = __fadd_rn(__fsub_rn(__fadd_rn(ai, aj), inter), 1e-9f);
        if (__fdiv_rn(inter, denom) > 0.5f) sup |= (1ull << il);
        else sup &= ~(1ull << il);
      }
    }
  }
  cols[w * 512 + jb * 64 + lane] = sup;
}

// ---------------- kernel 2: sort-all + NMS (no histogram) ----------------
__global__ __launch_bounds__(1024) void k2_class(const float* __restrict__ boxes,
                                                 const int* __restrict__ candCnt,
                                                 const u64* __restrict__ cand,
                                                 int* __restrict__ keptCnt,
                                                 u64* __restrict__ keptKeys,
                                                 u32* __restrict__ imgHist) {
  __shared__ float4 bx[512];
  __shared__ float areas[512];
  __shared__ u64 sbuf[1024];
  __shared__ u64 cols[8 * 512];
  __shared__ int s_stop;

  int tid = threadIdx.x;
  int wave = tid >> 6, lane = tid & 63;
  int bc = blockIdx.x;
  int b = bc / N_CLS, c = bc % N_CLS;
  int m = candCnt[bc];
  if (m > CAP) m = CAP;

  // load all candidates (m <= 1024 whp), sort descending -> top-500 = ranks 0..499
  u64 v = (tid < m) ? cand[(size_t)bc * CAP + tid] : 0;
  hybrid_sort<1024>(v, sbuf, tid);
  __syncthreads();
  sbuf[tid] = v;  // canonical sorted keys

  int V = m < KCAND ? m : KCAND;
  if (tid < 512) {
    float4 bxv = make_float4(0.f, 0.f, 0.f, 0.f);
    float ar = 0.f;
    if (tid < V) {
      u32 n = ~((u32)v);
      const float* bp = boxes + ((size_t)b * N_BOXES + n) * 4;
      bxv = make_float4(bp[0], bp[1], bp[2], bp[3]);
      ar = __fmul_rn(fmaxf(__fsub_rn(bxv.z, bxv.x), 0.0f), fmaxf(__fsub_rn(bxv.w, bxv.y), 0.0f));
    }
    bx[tid] = bxv;
    areas[tid] = ar;
  }
  __syncthreads();

  // interleaved mask tiles (16 waves/slot) + greedy scan with early stop
  const int ready[3] = {4, 6, 7};  // largest fully-masked chunk after each slot
  bool stop = false;
  int nextscan = 0, total = 0;
  u64 kmreg[8];
  for (int s = 0; s < 3; ++s) {
    if (!stop) {
      int T = s * 16 + wave;
      if (T < 36) {
        int jb = TILE_JB[T], w = TILE_W[T];
        if (w == jb) mask_tile<true>(bx, areas, cols, jb, w, lane, V);
        else mask_tile<false>(bx, areas, cols, jb, w, lane, V);
      }
    }
    __syncthreads();
    if (!stop && tid < 64) {
      int rmax = ready[s];
      while (nextscan <= rmax && nextscan * 64 < V && total < MAX_DET) {
        int dst = nextscan;
        int gj = dst * 64 + lane;
        bool sup = false;
        for (int src = 0; src < dst; ++src)
          if (cols[src * 512 + gj] & kmreg[src]) sup = true;
        u64 colw = cols[dst * 512 + gj];
        u64 supmask = __ballot(sup);
        // suppressor-skipping serial resolution: only candidates that suppress
        // someone (anysup, ~0.6/chunk) need ordered processing
        u64 anysup = wave_or64(colw);
        u64 rem = anysup & ~supmask;
        while (rem) {
          int i = __builtin_ctzll(rem);
          rem &= rem - 1;
          if (!((supmask >> i) & 1ull)) {
            u64 newsup = __ballot((int)((colw >> i) & 1ull));
            supmask |= newsup;
            rem &= ~supmask;
          }
        }
        int lim = V - dst * 64;
        if (lim > 64) lim = 64;
        u64 valid = (lim >= 64) ? ~0ull : ((1ull << lim) - 1ull);
        u64 keptm = ~supmask & valid;
        int rank = total + (int)__builtin_popcountll(keptm & ((1ull << lane) - 1ull));
        if (((keptm >> lane) & 1ull) && rank < MAX_DET) {
          u64 key = sbuf[gj];
          u32 sb = (u32)(key >> 32);
          u32 n = ~((u32)key);
          u32 flat = (u32)(c * KCAND + gj);
          keptKeys[(size_t)bc * 512 + rank] =
              ((u64)sb << 32) | ((u64)((~flat) & 0xFFFFu) << 16) | (u64)(n & 0xFFFFu);
          atomicAdd(&imgHist[b * 2048 + bin_of(sb)], 1u);
        }
        total += (int)__builtin_popcountll(keptm);
        kmreg[dst] = keptm;
        ++nextscan;
      }
      if (lane == 0) s_stop = (total >= MAX_DET) || (nextscan * 64 >= V) || (nextscan > 7);
    }
    __syncthreads();
    stop = (s_stop != 0);
    if (stop) break;
  }
  if (tid == 0) keptCnt[bc] = total < MAX_DET ? total : MAX_DET;
}

// ---------------- kernel 3: per-image global top-300 ----------------
__global__ __launch_bounds__(1024) void k3_image(const float* __restrict__ boxes,
                                                 const int* __restrict__ keptCnt,
                                                 const u64* __restrict__ keptKeys,
                                                 const u32* __restrict__ imgHist,
                                                 float* __restrict__ out) {
  __shared__ u32 hist[2048];
  __shared__ int partial[1024];
  __shared__ u64 sbuf[1024];
  __shared__ int kcs[N_CLS];
  __shared__ int s_t, s_cnt;
  int tid = threadIdx.x;
  int b = blockIdx.x;
  for (int i = tid; i < 2048; i += 1024) hist[i] = imgHist[b * 2048 + i];
  if (tid < N_CLS) kcs[tid] = keptCnt[b * N_CLS + tid];
  if (tid == 0) s_cnt = 0;
  __syncthreads();
  pick_threshold<1024>(hist, partial, &s_t, MAX_DET, tid);
  int t = s_t;
  const u64* kk = keptKeys + (size_t)b * N_CLS * 512;
  for (int idx = tid; idx < N_CLS * 512; idx += 1024) {
    int cc = idx >> 9, k = idx & 511;
    if (k < kcs[cc]) {
      u64 key = kk[(size_t)cc * 512 + k];
      if (bin_of((u32)(key >> 32)) >= t) {
        int p = atomicAdd(&s_cnt, 1);
        if (p < 1024) sbuf[p] = key;
      }
    }
  }
  __syncthreads();
  int cnt = s_cnt;
  if (cnt > 1024) cnt = 1024;
  u64 v = (tid < cnt) ? sbuf[tid] : 0;
  hybrid_sort<1024>(v, sbuf, tid);

  int V = cnt < MAX_DET ? cnt : MAX_DET;
  if (tid < MAX_DET) {
    float o0 = -1.f, o1 = -1.f, o2 = -1.f, o3 = -1.f, osc = -1.f, olb = -1.f;
    if (tid < V) {
      u32 sb = (u32)(v >> 32);
      u32 flat = (~((u32)(v >> 16))) & 0xFFFFu;
      u32 n = (u32)v & 0xFFFFu;
      const float* bp = boxes + ((size_t)b * N_BOXES + n) * 4;
      o0 = bp[0]; o1 = bp[1]; o2 = bp[2]; o3 = bp[3];
      osc = __uint_as_float(sb);
      olb = (float)(flat / KCAND);
    }
    size_t bs = (size_t)b * MAX_DET + tid;
    out[bs * 4 + 0] = o0;
    out[bs * 4 + 1] = o1;
    out[bs * 4 + 2] = o2;
    out[bs * 4 + 3] = o3;
    out[(size_t)N_IMG * MAX_DET * 4 + bs] = osc;
    out[(size_t)N_IMG * MAX_DET * 5 + bs] = olb;
  }
}

extern "C" void kernel_launch(void* const* d_in, const int* in_sizes, int n_in,
                              void* d_out, int out_size, void* d_ws, size_t ws_size,
                              hipStream_t stream) {
  const float* boxes = (const float*)d_in[0];
  const float* cls = (const float*)d_in[1];
  float* out = (float*)d_out;
  char* ws = (char*)d_ws;
  int* candCnt = (int*)(ws + OFF_CANDCNT);
  int* keptCnt = (int*)(ws + OFF_KEPTCNT);
  u32* imgHist = (u32*)(ws + OFF_IMGHIST);
  u64* keptKeys = (u64*)(ws + OFF_KEPTKEYS);
  u64* cand = (u64*)(ws + OFF_CAND);

  hipMemsetAsync(ws, 0, 73728, stream);  // candCnt + keptCnt + imgHist

  k1_compact<<<N_IMG * NGRP, 512, 0, stream>>>(cls, candCnt, cand);
  k2_class<<<N_IMG * N_CLS, 1024, 0, stream>>>(boxes, candCnt, cand, keptCnt, keptKeys, imgHist);
  k3_image<<<N_IMG, 1024, 0, stream>>>(boxes, keptCnt, keptKeys, imgHist, out);
}

// Round 8
// 300.509 us; speedup vs baseline: 1.1092x; 1.1092x over previous
//
#include <hip/hip_runtime.h>
#include <stdint.h>

typedef unsigned long long u64;
typedef unsigned int u32;

#define N_BOXES 50000
#define N_CLS 80
#define N_IMG 8
#define KCAND 500
#define MAX_DET 300
#define CAP 1024          // per-class candidates above 0.8: mean 692, sigma 26 -> +12.7 sigma
#define PRE_THR 0.8f

#define P_BOXES 512
#define NGRP ((N_BOXES + P_BOXES - 1) / P_BOXES)  // 98
#define BUFCAP 1024       // per-block passers: mean 567, sigma 24 -> +19 sigma

// workspace layout (bytes)
#define OFF_CANDCNT 0                      // 640*4 -> 2560
#define OFF_KEPTCNT 2560                   // 640*4 -> 5120
#define OFF_IMGHIST 8192                   // 8*2048*4 = 65536 -> 73728
#define OFF_KEPTKEYS 73728                 // 640*512*8 = 2621440 -> 2695168
#define OFF_CAND 2695168                   // 640*1024*8 = 5242880 -> 7938048

__device__ __forceinline__ int bin_of(u32 sb) {
  int d = (int)(sb - 0x3F000000u);
  int bin = d < 0 ? 0 : (d >> 12);
  return bin > 2047 ? 2047 : bin;
}

__device__ __forceinline__ u64 shflx64(u64 v, int m) {
  int lo = __shfl_xor((int)(u32)v, m, 64);
  int hi = __shfl_xor((int)(v >> 32), m, 64);
  return ((u64)(u32)hi << 32) | (u32)lo;
}

__device__ __forceinline__ u64 wave_or64(u64 v) {
  for (int m = 1; m < 64; m <<= 1) v |= shflx64(v, m);
  return v;
}

__device__ __forceinline__ void bstep(u64& v, u64 o, int idx, int k, int j) {
  bool takeMax = (((idx & k) == 0) == ((idx & j) == 0));
  if (takeMax ? (o > v) : (o < v)) v = o;
}

// 1024-elt descending bitonic over 512 threads, 2 elts/thread (vL=idx t, vU=idx t+512).
// j==512 is a register step; 64<=j<=256 LDS; j<64 shuffles.
__device__ __forceinline__ void sort1024_2elt(u64& vL, u64& vU, u64* sbuf, int t) {
  for (int k = 2; k <= 1024; k <<= 1)
    for (int j = k >> 1; j > 0; j >>= 1) {
      if (j == 512) {
        if (vU > vL) { u64 tmp = vL; vL = vU; vU = tmp; }
      } else if (j >= 64) {
        __syncthreads();
        sbuf[t] = vL;
        sbuf[t + 512] = vU;
        __syncthreads();
        u64 oL = sbuf[t ^ j], oU = sbuf[(t ^ j) + 512];
        bstep(vL, oL, t, k, j);
        bstep(vU, oU, t + 512, k, j);
      } else {
        bstep(vL, shflx64(vL, j), t, k, j);
        bstep(vU, shflx64(vU, j), t + 512, k, j);
      }
    }
}

// 1-elt/thread hybrid sort (used by k3)
template <int S>
__device__ __forceinline__ void hybrid_sort(u64& v, u64* sbuf, int tid) {
  for (int k = 2; k <= S; k <<= 1)
    for (int j = k >> 1; j > 0; j >>= 1) {
      u64 o;
      if (j >= 64) {
        __syncthreads();
        sbuf[tid] = v;
        __syncthreads();
        o = sbuf[tid ^ j];
      } else {
        o = shflx64(v, j);
      }
      bool takeMax = (((tid & k) == 0) == ((tid & j) == 0));
      if (takeMax ? (o > v) : (o < v)) v = o;
    }
}

template <int T>
__device__ __forceinline__ void pick_threshold(u32* hist, int* partial, int* s_t, int K, int tid) {
  constexpr int G = 2048 / T;
  int ps = 0;
#pragma unroll
  for (int q = 0; q < G; ++q) ps += (int)hist[tid * G + q];
  partial[tid] = ps;
  for (int off = 1; off < T; off <<= 1) {
    __syncthreads();
    int v = partial[tid];
    if (tid + off < T) v += partial[tid + off];
    __syncthreads();
    partial[tid] = v;
  }
  if (tid == 0) *s_t = 0;
  __syncthreads();
  int sfx = partial[tid];
  int nxt = (tid == T - 1) ? 0 : partial[tid + 1];
  if (sfx >= K && nxt < K) {
    int acc = nxt;
    int bin;
    for (bin = tid * G + G - 1; bin > tid * G; --bin) {
      if (acc + (int)hist[bin] >= K) break;
      acc += (int)hist[bin];
    }
    *s_t = bin;
  }
  __syncthreads();
}

// exact RN(inter/denom) > 0.5 with guard band + rare exact-div fallback
__device__ __forceinline__ bool iou_sup(float4 bi, float4 bj) {
  float ai = __fmul_rn(fmaxf(__fsub_rn(bi.z, bi.x), 0.f), fmaxf(__fsub_rn(bi.w, bi.y), 0.f));
  float aj = __fmul_rn(fmaxf(__fsub_rn(bj.z, bj.x), 0.f), fmaxf(__fsub_rn(bj.w, bj.y), 0.f));
  float ih = fmaxf(__fsub_rn(fminf(bi.z, bj.z), fmaxf(bi.x, bj.x)), 0.f);
  float iw = fmaxf(__fsub_rn(fminf(bi.w, bj.w), fmaxf(bi.y, bj.y)), 0.f);
  float inter = __fmul_rn(ih, iw);
  float denom = __fadd_rn(__fsub_rn(__fadd_rn(ai, aj), inter), 1e-9f);
  float diff = __fsub_rn(__fmul_rn(inter, 2.f), denom);
  if (fabsf(diff) > __fmul_rn(denom, 1e-6f)) return diff > 0.f;
  return __fdiv_rn(inter, denom) > 0.5f;
}

// ---------------- kernel 1: candidate compaction (coalesced) ----------------
// key = score_bits<<32 | (~n & 0xFFFF)<<16 | c   (c constant within a class sort)
__global__ __launch_bounds__(512) void k1_compact(const float* __restrict__ cls,
                                                  int* __restrict__ candCnt,
                                                  u64* __restrict__ cand) {
  __shared__ u64 bkey[BUFCAP];
  __shared__ int cnt[N_CLS];
  __shared__ int cbase[N_CLS];
  __shared__ int cur[N_CLS];
  __shared__ int s_n;

  int tid = threadIdx.x;
  int lane = tid & 63;
  int b = blockIdx.x / NGRP, g = blockIdx.x % NGRP;
  int n0 = g * P_BOXES;
  int nb = N_BOXES - n0;
  if (nb > P_BOXES) nb = P_BOXES;
  int nf4 = nb * (N_CLS / 4);
  const float4* src = (const float4*)(cls + ((size_t)b * N_BOXES + n0) * N_CLS);

  for (int i = tid; i < N_CLS; i += 512) { cnt[i] = 0; cur[i] = 0; }
  if (tid == 0) s_n = 0;
  __syncthreads();

  // 1 float4/thread/iter: lane addresses are 16B-contiguous -> perfectly coalesced
  for (int i = tid; i < nf4; i += 512) {
    float4 s4 = src[i];
    int nl = i / 20;                 // 20 float4 per 80-class row
    int cb = (i - nl * 20) * 4;
    u32 pack = (((u32)(~(u32)(n0 + nl)) & 0xFFFFu) << 16);
    bool p0 = s4.x > PRE_THR, p1 = s4.y > PRE_THR, p2 = s4.z > PRE_THR, p3 = s4.w > PRE_THR;
    u64 m0 = __ballot(p0), m1 = __ballot(p1), m2 = __ballot(p2), m3 = __ballot(p3);
    int w0 = __builtin_popcountll(m0), w1 = __builtin_popcountll(m1);
    int w2 = __builtin_popcountll(m2), w3 = __builtin_popcountll(m3);
    int tc = w0 + w1 + w2 + w3;
    if (tc) {  // ONE atomic+shfl per float4 (was 4)
      int basep = 0;
      if (lane == 0) basep = atomicAdd(&s_n, tc);
      basep = __shfl(basep, 0);
      u64 lm = (1ull << lane) - 1ull;
      if (p0) {
        int pos = basep + __builtin_popcountll(m0 & lm);
        if (pos < BUFCAP) { bkey[pos] = ((u64)__float_as_uint(s4.x) << 32) | pack | (u32)(cb + 0); atomicAdd(&cnt[cb + 0], 1); }
      }
      if (p1) {
        int pos = basep + w0 + __builtin_popcountll(m1 & lm);
        if (pos < BUFCAP) { bkey[pos] = ((u64)__float_as_uint(s4.y) << 32) | pack | (u32)(cb + 1); atomicAdd(&cnt[cb + 1], 1); }
      }
      if (p2) {
        int pos = basep + w0 + w1 + __builtin_popcountll(m2 & lm);
        if (pos < BUFCAP) { bkey[pos] = ((u64)__float_as_uint(s4.z) << 32) | pack | (u32)(cb + 2); atomicAdd(&cnt[cb + 2], 1); }
      }
      if (p3) {
        int pos = basep + w0 + w1 + w2 + __builtin_popcountll(m3 & lm);
        if (pos < BUFCAP) { bkey[pos] = ((u64)__float_as_uint(s4.w) << 32) | pack | (u32)(cb + 3); atomicAdd(&cnt[cb + 3], 1); }
      }
    }
  }
  __syncthreads();
  int total = s_n < BUFCAP ? s_n : BUFCAP;
  if (tid < N_CLS) {
    int n = cnt[tid];
    cbase[tid] = n ? atomicAdd(&candCnt[b * N_CLS + tid], n) : 0;
  }
  __syncthreads();
  for (int i = tid; i < total; i += 512) {
    u64 key = bkey[i];
    int c = (int)(key & 0x7F);
    int w = atomicAdd(&cur[c], 1);
    int pos = cbase[c] + w;
    if (pos < CAP) cand[(size_t)(b * N_CLS + c) * CAP + pos] = key;
  }
}

// fast-path tiles: (jb, w), w <= jb, jb <= 4  (15 tiles, scan window 320)
__device__ const unsigned char TJB[15] = {0, 1,1, 2,2,2, 3,3,3,3, 4,4,4,4,4};
__device__ const unsigned char TW[15]  = {0, 0,1, 0,1,2, 0,1,2,3, 0,1,2,3,4};

#define COLS_STRIDE 320

template <bool DIAG>
__device__ __forceinline__ void mask_tile(const float4* bx, u64* cols, int jb, int w,
                                          int lane, int V) {
  int j = jb * 64 + lane;
  u64 sup = 0;
  if (j < V) {
    float4 bj = bx[j];
    float aj = __fmul_rn(fmaxf(__fsub_rn(bj.z, bj.x), 0.f), fmaxf(__fsub_rn(bj.w, bj.y), 0.f));
    const float4* bp = bx + w * 64;
    u64 needs = 0;
#pragma unroll 16
    for (int il = 0; il < 64; ++il) {
      float4 bi = bp[il];  // immediate-offset ds_read_b128, same-address broadcast
      float ai = __fmul_rn(fmaxf(__fsub_rn(bi.z, bi.x), 0.f), fmaxf(__fsub_rn(bi.w, bi.y), 0.f));
      float yy1 = fmaxf(bi.x, bj.x);
      float xx1 = fmaxf(bi.y, bj.y);
      float yy2 = fminf(bi.z, bj.z);
      float xx2 = fminf(bi.w, bj.w);
      float ih = fmaxf(__fsub_rn(yy2, yy1), 0.0f);
      float iw = fmaxf(__fsub_rn(xx2, xx1), 0.0f);
      float inter = __fmul_rn(ih, iw);
      float denom = __fadd_rn(__fsub_rn(__fadd_rn(ai, aj), inter), 1e-9f);
      float diff = __fsub_rn(__fmul_rn(inter, 2.0f), denom);
      bool fast = diff > 0.0f;
      bool nd = fabsf(diff) <= __fmul_rn(denom, 1e-6f);
      if (DIAG) { bool lt = il < lane; fast = fast && lt; nd = nd && lt; }
      sup |= fast ? (1ull << il) : 0ull;
      needs |= nd ? (1ull << il) : 0ull;
    }
    if (needs) {
      u64 nm = needs;
      while (nm) {
        int il = __builtin_ctzll(nm);
        nm &= nm - 1;
        if (iou_sup(bp[il], bj)) sup |= (1ull << il);
        else sup &= ~(1ull << il);
      }
    }
  }
  cols[w * COLS_STRIDE + jb * 64 + lane] = sup;
}

// ---------------- kernel 2: sort-all + NMS ----------------
__global__ __launch_bounds__(512) void k2_class(const float* __restrict__ boxes,
                                                const int* __restrict__ candCnt,
                                                const u64* __restrict__ cand,
                                                int* __restrict__ keptCnt,
                                                u64* __restrict__ keptKeys,
                                                u32* __restrict__ imgHist) {
  __shared__ u64 sbuf[1024];            // 8 KB
  __shared__ float4 bx[512];            // 8 KB
  __shared__ u64 cols[5 * COLS_STRIDE]; // 12.8 KB  -> total ~29 KB, 4 blocks/CU
  int tid = threadIdx.x;
  int lane = tid & 63, wave = tid >> 6;
  int bc = blockIdx.x;
  int b = bc / N_CLS, c = bc % N_CLS;
  int m = candCnt[bc];
  if (m > CAP) m = CAP;
  const u64* my = cand + (size_t)bc * CAP;

  u64 vL = (tid < m) ? my[tid] : 0;
  u64 vU = (tid + 512 < m) ? my[tid + 512] : 0;
  sort1024_2elt(vL, vU, sbuf, tid);   // vL = rank-tid element (descending)

  int V = m < KCAND ? m : KCAND;
  __syncthreads();
  sbuf[tid] = vL;  // ranks 0..511 (only <V used)
  float4 bxv = make_float4(0.f, 0.f, 0.f, 0.f);
  if (tid < V) {
    u32 n = (~(u32)(vL >> 16)) & 0xFFFFu;
    const float* bp = boxes + ((size_t)b * N_BOXES + n) * 4;
    bxv = make_float4(bp[0], bp[1], bp[2], bp[3]);
  }
  bx[tid] = bxv;
  __syncthreads();

  // mask: 15 tiles over 8 waves, one slot
  for (int idx = wave; idx < 15; idx += 8) {
    int jb = TJB[idx], w = TW[idx];
    if (w == jb) mask_tile<true>(bx, cols, jb, w, lane, V);
    else mask_tile<false>(bx, cols, jb, w, lane, V);
  }
  __syncthreads();

  // greedy scan, wave 0; chunks 0-4 from cols, 5-7 on-the-fly (rare)
  if (tid < 64) {
    u64 kmreg[8];
    int total = 0;
    for (int dst = 0; dst < 8 && dst * 64 < V && total < MAX_DET; ++dst) {
      int gj = dst * 64 + lane;
      bool act = gj < V;
      float4 bg = bx[act ? gj : 0];
      bool sup = false;
      u64 colw = 0;
      if (dst <= 4) {
        for (int src = 0; src < dst; ++src)
          if (cols[src * COLS_STRIDE + gj] & kmreg[src]) sup = true;
        colw = cols[dst * COLS_STRIDE + gj];
      } else {
        // fallback: compute suppression on the fly vs kept-so-far + in-chunk
        for (int src = 0; src < dst; ++src) {
          u64 km = kmreg[src];
          while (km) {
            int i = __builtin_ctzll(km);
            km &= km - 1;
            if (act && iou_sup(bx[src * 64 + i], bg)) sup = true;
          }
        }
        for (int il = 0; il < 64; ++il)
          if (il < lane && act && iou_sup(bx[dst * 64 + il], bg)) colw |= (1ull << il);
      }
      u64 supmask = __ballot(sup);
      u64 anysup = wave_or64(colw);
      u64 rem = anysup & ~supmask;
      while (rem) {
        int i = __builtin_ctzll(rem);
        rem &= rem - 1;
        if (!((supmask >> i) & 1ull)) {
          supmask |= __ballot((int)((colw >> i) & 1ull));
          rem &= ~supmask;
        }
      }
      int lim = V - dst * 64;
      if (lim > 64) lim = 64;
      u64 valid = (lim >= 64) ? ~0ull : ((1ull << lim) - 1ull);
      u64 keptm = ~supmask & valid;
      int rank = total + (int)__builtin_popcountll(keptm & ((1ull << lane) - 1ull));
      if (((keptm >> lane) & 1ull) && rank < MAX_DET) {
        u64 key = sbuf[gj];
        u32 sb = (u32)(key >> 32);
        u32 n = (~(u32)(key >> 16)) & 0xFFFFu;
        u32 flat = (u32)(c * KCAND + gj);
        keptKeys[(size_t)bc * 512 + rank] =
            ((u64)sb << 32) | ((u64)((~flat) & 0xFFFFu) << 16) | (u64)n;
        atomicAdd(&imgHist[b * 2048 + bin_of(sb)], 1u);
      }
      total += (int)__builtin_popcountll(keptm);
      kmreg[dst] = keptm;
    }
    if (lane == 0) keptCnt[bc] = total < MAX_DET ? total : MAX_DET;
  }
}

// ---------------- kernel 3: per-image global top-300 ----------------
__global__ __launch_bounds__(1024) void k3_image(const float* __restrict__ boxes,
                                                 const int* __restrict__ keptCnt,
                                                 const u64* __restrict__ keptKeys,
                                                 const u32* __restrict__ imgHist,
                                                 float* __restrict__ out) {
  __shared__ u32 hist[2048];
  __shared__ int partial[1024];
  __shared__ u64 sbuf[1024];
  __shared__ int kcs[N_CLS];
  __shared__ int s_t, s_cnt;
  int tid = threadIdx.x;
  int b = blockIdx.x;
  for (int i = tid; i < 2048; i += 1024) hist[i] = imgHist[b * 2048 + i];
  if (tid < N_CLS) kcs[tid] = keptCnt[b * N_CLS + tid];
  if (tid == 0) s_cnt = 0;
  __syncthreads();
  pick_threshold<1024>(hist, partial, &s_t, MAX_DET, tid);
  int t = s_t;
  const u64* kk = keptKeys + (size_t)b * N_CLS * 512;
  for (int idx = tid; idx < N_CLS * 512; idx += 1024) {
    int cc = idx >> 9, k = idx & 511;
    if (k < kcs[cc]) {
      u64 key = kk[(size_t)cc * 512 + k];
      if (bin_of((u32)(key >> 32)) >= t) {
        int p = atomicAdd(&s_cnt, 1);
        if (p < 1024) sbuf[p] = key;
      }
    }
  }
  __syncthreads();
  int cnt = s_cnt;
  if (cnt > 1024) cnt = 1024;
  u64 v = (tid < cnt) ? sbuf[tid] : 0;
  hybrid_sort<1024>(v, sbuf, tid);

  int V = cnt < MAX_DET ? cnt : MAX_DET;
  if (tid < MAX_DET) {
    float o0 = -1.f, o1 = -1.f, o2 = -1.f, o3 = -1.f, osc = -1.f, olb = -1.f;
    if (tid < V) {
      u32 sb = (u32)(v >> 32);
      u32 flat = (~((u32)(v >> 16))) & 0xFFFFu;
      u32 n = (u32)v & 0xFFFFu;
      const float* bp = boxes + ((size_t)b * N_BOXES + n) * 4;
      o0 = bp[0]; o1 = bp[1]; o2 = bp[2]; o3 = bp[3];
      osc = __uint_as_float(sb);
      olb = (float)(flat / KCAND);
    }
    size_t bs = (size_t)b * MAX_DET + tid;
    out[bs * 4 + 0] = o0;
    out[bs * 4 + 1] = o1;
    out[bs * 4 + 2] = o2;
    out[bs * 4 + 3] = o3;
    out[(size_t)N_IMG * MAX_DET * 4 + bs] = osc;
    out[(size_t)N_IMG * MAX_DET * 5 + bs] = olb;
  }
}

extern "C" void kernel_launch(void* const* d_in, const int* in_sizes, int n_in,
                              void* d_out, int out_size, void* d_ws, size_t ws_size,
                              hipStream_t stream) {
  const float* boxes = (const float*)d_in[0];
  const float* cls = (const float*)d_in[1];
  float* out = (float*)d_out;
  char* ws = (char*)d_ws;
  int* candCnt = (int*)(ws + OFF_CANDCNT);
  int* keptCnt = (int*)(ws + OFF_KEPTCNT);
  u32* imgHist = (u32*)(ws + OFF_IMGHIST);
  u64* keptKeys = (u64*)(ws + OFF_KEPTKEYS);
  u64* cand = (u64*)(ws + OFF_CAND);

  hipMemsetAsync(ws, 0, 73728, stream);  // candCnt + keptCnt + imgHist

  k1_compact<<<N_IMG * NGRP, 512, 0, stream>>>(cls, candCnt, cand);
  k2_class<<<N_IMG * N_CLS, 512, 0, stream>>>(boxes, candCnt, cand, keptCnt, keptKeys, imgHist);
  k3_image<<<N_IMG, 1024, 0, stream>>>(boxes, keptCnt, keptKeys, imgHist, out);
}